// Round 10
// baseline (356.090 us; speedup 1.0000x reference)
//
#include <hip/hip_runtime.h>
#include <hip/hip_bf16.h>

#define N 2048
#define NM1 2047
#define DT 256
#define ET 32
#define EC 128
#define NC 5
#define FS 80    // feats row stride (floats)
#define FD 69    // used feature cols
#define KC_ET 16 // k-chunks for ET GEMMs (chunk = 128)
#define KC_EC 16 // k-chunks for EC GEMM (chunk = 128)
#define NB 256   // mega-kernel grid = CU count (co-residency by construction)

typedef __hip_bfloat16 bf16;

__device__ __forceinline__ void gridbar(int* cnt, int target){
    __syncthreads();
    if (threadIdx.x == 0){
        __threadfence();                       // release: L2 writeback
        atomicAdd(cnt, 1);
        while (atomicAdd(cnt, 0) < target) __builtin_amdgcn_s_sleep(1);
        __threadfence();                       // acquire: invalidate stale
    }
    __syncthreads();
}

__global__ __launch_bounds__(256, 1)
void k_mega(const float* __restrict__ tw, const float* __restrict__ fw,
            const int* __restrict__ labels,
            const float* __restrict__ Xt, const float* __restrict__ Wt,
            const float* __restrict__ Xf, const float* __restrict__ Wf,
            const float* __restrict__ bt, const float* __restrict__ bfv,
            const int* __restrict__ qsize,
            const float* __restrict__ Wc, const float* __restrict__ bc,
            const float* __restrict__ Wo, const float* __restrict__ bo,
            float* degT, float* degF, float* dsum, int* cnt, float* colsb,
            float* Yt, float* Yf, float* Zc, float* feats, float* Aw,
            float* Pt, float* Pf, float* Pe, float* out){
    __shared__ float lds[32768];   // 128 KB, re-sliced per phase
    int b = blockIdx.x;
    int t = threadIdx.x;

    // ===== phase 0: deg (v<512) + labelmask (v==512) + X@W (v>512) =====
    for (int v = b; v < 1025; v += NB){
        if (v < 512){
            int p = (v & 7)*256 + t;
            if (p < NM1){
                int s0 = (v >> 3)*32;
                float lowT=0.f, highT=0.f, lowF=0.f, highF=0.f;
                #pragma unroll 8
                for (int r = 0; r < 32; ++r){
                    int s = s0 + r;
                    float vt = tw[(size_t)s*NM1 + p];
                    float vf = fw[(size_t)s*NM1 + p];
                    if (s <= p){ highT += vt; highF += vf; }
                    else       { lowT  += vt; lowF  += vf; }
                }
                atomicAdd(&degT[p],   lowT);
                atomicAdd(&degF[p],   lowF);
                atomicAdd(&degT[p+1], highT);
                atomicAdd(&degF[p+1], highF);
            }
        } else if (v == 512){
            float* lc = lds;
            if (t < NC) lc[t] = 0.f;
            __syncthreads();
            for (int i = t; i < N; i += 256){
                int l = labels[i];
                if (l >= 0 && l < NC) lc[l] = 1.f;
            }
            __syncthreads();
            if (t < NC) colsb[t] = lc[t];
            __syncthreads();
        } else {
            int idx = v - 513;
            const float* X = (idx & 256) ? Xf : Xt;
            const float* W = (idx & 256) ? Wf : Wt;
            float*       Y = (idx & 256) ? Yf : Yt;
            float* Ws = lds;          // 8192
            float* Xs = lds + 8192;   // 2048
            for (int j = t; j < DT*ET; j += 256) Ws[j] = W[j];
            int i0 = (idx & 255)*8;
            for (int j = t; j < 8*DT; j += 256) Xs[j] = X[(size_t)i0*DT + j];
            __syncthreads();
            int r = t >> 5, f = t & 31;
            const float* xr = Xs + r*DT;
            float acc = 0.f;
            #pragma unroll 8
            for (int d = 0; d < DT; ++d) acc += xr[d]*Ws[d*ET+f];
            Y[(size_t)(i0+r)*ET+f] = acc;
            __syncthreads();
        }
    }
    gridbar(cnt, 1*NB);

    // ===== phase 1: agg_et (2 virtual: 32 i-blocks x 16 kc) =====
    {
        float* Ast = lds;                        // 64*68
        float* Asf = lds + 64*68;
        float* Zst = lds + 2*64*68;              // 64*32
        float* Zsf = lds + 2*64*68 + 64*32;
        int g  = t >> 7;
        int tt = t & 127;
        int ig = tt >> 3, fg = tt & 7;
        int r0 = ig*4, c0 = fg*4;
        const float* As = g ? Asf : Ast;
        const float* Zs = g ? Zsf : Zst;
        for (int vv = 0; vv < 2; ++vv){
            int v = b*2 + vv;
            int i0 = (v & 31)*64;
            int kc = v >> 5;
            int k0 = kc*128;
            float acc[4][4];
            #pragma unroll
            for (int u=0;u<4;++u)
                #pragma unroll
                for (int w=0;w<4;++w) acc[u][w]=0.f;
            for (int kt = 0; kt < 2; ++kt){
                int kb = k0 + kt*64;
                #pragma unroll
                for (int e = 0; e < 16; ++e){
                    int id = t + e*256;
                    int k_l = id >> 6, i_l = id & 63;
                    int k = kb + k_l;
                    int gi = i0 + i_l;
                    float vt, vf;
                    if (gi == k){ vt = 0.f; vf = 0.f; }
                    else {
                        size_t base = (size_t)k*NM1 + gi - (gi > k ? 1 : 0);
                        vt = tw[base]; vf = fw[base];
                    }
                    Ast[k_l*68 + i_l] = vt;
                    Asf[k_l*68 + i_l] = vf;
                }
                #pragma unroll
                for (int e = 0; e < 2; ++e){
                    int id = t + e*256;
                    int row = id >> 3;
                    int c4  = (id & 7)*4;
                    float rdT = rsqrtf(1.f + degT[kb+row]);
                    float rdF = rsqrtf(1.f + degF[kb+row]);
                    float4 yt = *(const float4*)&Yt[(size_t)(kb+row)*ET + c4];
                    float4 yf = *(const float4*)&Yf[(size_t)(kb+row)*ET + c4];
                    yt.x*=rdT; yt.y*=rdT; yt.z*=rdT; yt.w*=rdT;
                    yf.x*=rdF; yf.y*=rdF; yf.z*=rdF; yf.w*=rdF;
                    *(float4*)&Zst[row*ET + c4] = yt;
                    *(float4*)&Zsf[row*ET + c4] = yf;
                }
                __syncthreads();
                for (int k = 0; k < 64; ++k){
                    float4 a = *(const float4*)&As[k*68 + r0];
                    float4 z = *(const float4*)&Zs[k*ET + c0];
                    const float* ap = (const float*)&a;
                    const float* zp = (const float*)&z;
                    #pragma unroll
                    for (int u = 0; u < 4; ++u)
                        #pragma unroll
                        for (int w = 0; w < 4; ++w)
                            acc[u][w] += ap[u]*zp[w];
                }
                __syncthreads();
            }
            float* P = g ? Pf : Pt;
            #pragma unroll
            for (int u = 0; u < 4; ++u){
                size_t ii = (size_t)(i0 + r0 + u);
                float4 o;
                float* po = (float*)&o;
                #pragma unroll
                for (int w = 0; w < 4; ++w) po[w]=acc[u][w];
                *(float4*)&P[(size_t)kc*(N*ET) + ii*ET + c0] = o;
            }
        }
    }
    gridbar(cnt, 2*NB);

    // ===== phase 2: feats_epi (2 virtual) =====
    for (int vv = 0; vv < 2; ++vv){
        int idx = (b*2+vv)*256 + t;   // over 2048*64
        int i = idx >> 6;
        int f = idx & 63;
        float s, rd, bb;
        if (f < ET){
            rd = rsqrtf(1.f + degT[i]);
            s = rd*Yt[(size_t)i*ET + f];
            #pragma unroll
            for (int kc = 0; kc < KC_ET; ++kc) s += Pt[(size_t)kc*(N*ET) + (size_t)i*ET + f];
            bb = bt[f];
        } else {
            int g2 = f - ET;
            rd = rsqrtf(1.f + degF[i]);
            s = rd*Yf[(size_t)i*ET + g2];
            #pragma unroll
            for (int kc = 0; kc < KC_ET; ++kc) s += Pf[(size_t)kc*(N*ET) + (size_t)i*ET + g2];
            bb = bfv[g2];
        }
        float vx = rd*s + bb;
        feats[(size_t)i*FS + f] = vx > 0.f ? vx : 0.01f*vx;
        if (f < NC){
            int nsup = N - qsize[0];
            feats[(size_t)i*FS + 2*ET + f] = (i < nsup) ? colsb[f] : 0.f;
        }
    }
    gridbar(cnt, 3*NB);

    // ===== phase 3: build_aw (4 virtual: 32x32 tile grid) =====
    {
        float* fiT = lds;              // 64*68
        float* fjT = lds + 64*68;
        int tx = t & 15, ty = t >> 4;
        for (int vv = 0; vv < 4; ++vv){
            int v = b*4 + vv;
            int i0 = (v & 31)*64, j0 = (v >> 5)*64;
            {
                int row = t >> 2;
                int cb  = (t & 3)*16;
                const float4* si = (const float4*)(feats + (size_t)(i0+row)*FS + cb);
                const float4* sj = (const float4*)(feats + (size_t)(j0+row)*FS + cb);
                #pragma unroll
                for (int s = 0; s < 4; ++s){
                    float4 vx = si[s];
                    float4 w = sj[s];
                    int c = cb + s*4;
                    fiT[(c+0)*68+row]=vx.x; fiT[(c+1)*68+row]=vx.y; fiT[(c+2)*68+row]=vx.z; fiT[(c+3)*68+row]=vx.w;
                    fjT[(c+0)*68+row]=w.x;  fjT[(c+1)*68+row]=w.y;  fjT[(c+2)*68+row]=w.z;  fjT[(c+3)*68+row]=w.w;
                }
            }
            __syncthreads();
            float acc[4][4];
            #pragma unroll
            for (int u=0;u<4;++u)
                #pragma unroll
                for (int w=0;w<4;++w) acc[u][w]=0.f;
            for (int d = 0; d < 64; ++d){
                float4 a4 = *(const float4*)&fiT[d*68 + ty*4];
                float4 b4 = *(const float4*)&fjT[d*68 + tx*4];
                const float* ap = (const float*)&a4;
                const float* bp = (const float*)&b4;
                #pragma unroll
                for (int u = 0; u < 4; ++u)
                    #pragma unroll
                    for (int w = 0; w < 4; ++w)
                        acc[u][w] += fabsf(ap[u]-bp[w]);
            }
            #pragma unroll
            for (int u = 0; u < 4; ++u){
                int gi = i0 + ty*4 + u;
                float4 o;
                float* po = (float*)&o;
                #pragma unroll
                for (int w = 0; w < 4; ++w){
                    int gj = j0 + tx*4 + w;
                    po[w] = (gi==gj) ? 1.0f : 1.0f/(acc[u][w] + 1e-5f);
                }
                *(float4*)&Aw[(size_t)gi*N + j0 + tx*4] = o;
                float rs = (po[0]+po[1]) + (po[2]+po[3]);
                rs += __shfl_xor(rs, 1);
                rs += __shfl_xor(rs, 2);
                rs += __shfl_xor(rs, 4);
                rs += __shfl_xor(rs, 8);
                if (tx == 0) atomicAdd(&dsum[gi], rs);
            }
            __syncthreads();
        }
    }
    gridbar(cnt, 4*NB);

    // ===== phase 4: featswc (1 virtual) =====
    {
        float* Wcs = lds;             // FD*EC = 8832
        float* fr  = lds + 8832;      // 8*(FD+3) = 576
        for (int idx = t; idx < FD*EC; idx += 256) Wcs[idx] = Wc[idx];
        int i0 = b*8;
        for (int idx = t; idx < 8*FD; idx += 256){
            int r = idx / FD;
            int c = idx - r*FD;
            fr[r*(FD+3) + c] = feats[(size_t)(i0+r)*FS + c];
        }
        __syncthreads();
        int f  = t & 127;
        int rh = t >> 7;
        for (int rr = 0; rr < 4; ++rr){
            int r = rh*4 + rr;
            float acc = 0.f;
            #pragma unroll
            for (int d = 0; d < FD; ++d) acc += fr[r*(FD+3)+d]*Wcs[d*EC+f];
            int i = i0 + r;
            Zc[(size_t)i*EC + f] = rsqrtf(dsum[i])*acc;
        }
        __syncthreads();
    }
    gridbar(cnt, 5*NB);

    // ===== phase 5: agg_ec (1 virtual: 16 i-blocks x 16 kc) =====
    {
        float* As = lds;              // 128*128
        float* Zs = lds + 16384;      // 128*128
        int i0 = (b & 15)*128;
        int kc = b >> 4;
        int k0 = kc*128;
        int rg = t >> 4;
        int cg = t & 15;
        int r0 = rg*8;
        int ca = cg*4, cb2 = 64 + cg*4;
        #pragma unroll
        for (int e = 0; e < 16; ++e){
            int id = t + e*256;
            int k_l = id >> 5;
            int i4  = (id & 31)*4;
            *(float4*)&As[k_l*128 + i4] = *(const float4*)&Aw[(size_t)(k0+k_l)*N + i0 + i4];
        }
        #pragma unroll
        for (int e = 0; e < 16; ++e){
            int id = t + e*256;
            int k_l = id >> 5;
            int c4  = (id & 31)*4;
            *(float4*)&Zs[k_l*128 + c4] = *(const float4*)&Zc[(size_t)(k0+k_l)*EC + c4];
        }
        __syncthreads();
        float acc[8][8];
        #pragma unroll
        for (int u=0;u<8;++u)
            #pragma unroll
            for (int w=0;w<8;++w) acc[u][w]=0.f;
        for (int k = 0; k < 128; ++k){
            float4 a0 = *(const float4*)&As[k*128 + r0];
            float4 a1 = *(const float4*)&As[k*128 + r0 + 4];
            float4 z0 = *(const float4*)&Zs[k*128 + ca];
            float4 z1 = *(const float4*)&Zs[k*128 + cb2];
            float a8[8] = {a0.x,a0.y,a0.z,a0.w,a1.x,a1.y,a1.z,a1.w};
            float zl[4] = {z0.x,z0.y,z0.z,z0.w};
            float zh[4] = {z1.x,z1.y,z1.z,z1.w};
            #pragma unroll
            for (int u = 0; u < 8; ++u){
                #pragma unroll
                for (int w = 0; w < 4; ++w){
                    acc[u][w]   += a8[u]*zl[w];
                    acc[u][w+4] += a8[u]*zh[w];
                }
            }
        }
        #pragma unroll
        for (int u = 0; u < 8; ++u){
            size_t ii = (size_t)(i0 + r0 + u);
            float4 o0, o1;
            float* p0 = (float*)&o0; float* p1 = (float*)&o1;
            #pragma unroll
            for (int w = 0; w < 4; ++w){ p0[w]=acc[u][w]; p1[w]=acc[u][w+4]; }
            *(float4*)&Pe[(size_t)kc*(N*EC) + ii*EC + ca]  = o0;
            *(float4*)&Pe[(size_t)kc*(N*EC) + ii*EC + cb2] = o1;
        }
        __syncthreads();
    }
    gridbar(cnt, 6*NB);

    // ===== phase 6: embfinal (4 virtual) =====
    {
        float* Wos = lds;             // 640
        float* bos = lds + 640;       // 8
        float* vs  = lds + 656;       // 2*128
        for (int idx = t; idx < EC*NC; idx += 256) Wos[idx] = Wo[idx];
        if (t < NC) bos[t] = bo[t];
        __syncthreads();
        int rr = t >> 7, f = t & 127;
        for (int vv = 0; vv < 4; ++vv){
            int v = b*4 + vv;
            int i = v*2 + rr;
            size_t idx = (size_t)i*EC + f;
            float s = 0.f;
            #pragma unroll
            for (int kc = 0; kc < KC_EC; ++kc) s += Pe[(size_t)kc*(N*EC) + idx];
            float vx = rsqrtf(dsum[i])*s + bc[f];
            vs[rr*EC + f] = vx > 0.f ? vx : 0.01f*vx;
            __syncthreads();
            if (t < 2*NC){
                int r = t / NC;
                int c = t - r*NC;
                float a = bos[c];
                #pragma unroll 8
                for (int f2 = 0; f2 < EC; ++f2) a += vs[r*EC+f2]*Wos[f2*NC+c];
                out[(size_t)(v*2 + r)*NC + c] = a;
            }
            __syncthreads();
        }
    }
}

extern "C" void kernel_launch(void* const* d_in, const int* in_sizes, int n_in,
                              void* d_out, int out_size, void* d_ws, size_t ws_size,
                              hipStream_t stream) {
    const float* time_features = (const float*)d_in[0];
    const float* tw            = (const float*)d_in[2];
    const float* freq_features = (const float*)d_in[3];
    const float* fw            = (const float*)d_in[4];
    const int*   labels        = (const int*)d_in[5];
    const int*   qsize         = (const int*)d_in[7];
    const float* Wt  = (const float*)d_in[8];
    const float* bt  = (const float*)d_in[9];
    const float* Wf  = (const float*)d_in[10];
    const float* bfv = (const float*)d_in[11];
    const float* Wc  = (const float*)d_in[12];
    const float* bc  = (const float*)d_in[13];
    const float* Wo  = (const float*)d_in[14];
    const float* bo  = (const float*)d_in[15];
    float* out = (float*)d_out;

    float* ws    = (float*)d_ws;
    float* degT  = ws;                         // N (zeroed)
    float* degF  = degT + N;                   // N (zeroed)
    float* dsum  = degF + N;                   // N (zeroed)
    int*   cnt   = (int*)(dsum + N);           // 4 ints (zeroed)
    float* colsb = dsum + N + 4;               // 8
    float* Yt    = colsb + 12;                 // N*ET
    float* Yf    = Yt + (size_t)N*ET;          // N*ET
    float* Zc    = Yf + (size_t)N*ET;          // N*EC
    float* feats = Zc + (size_t)N*EC;          // N*FS
    float* Aw    = feats + (size_t)N*FS;       // N*N
    float* Pt    = Aw + (size_t)N*N;           // KC_ET*N*ET
    float* Pf    = Pt + (size_t)KC_ET*N*ET;    // KC_ET*N*ET
    float* Pe    = Pf + (size_t)KC_ET*N*ET;    // KC_EC*N*EC

    hipMemsetAsync(degT, 0, (3*N+4)*sizeof(float), stream);
    k_mega<<<NB, 256, 0, stream>>>(tw, fw, labels,
                                   time_features, Wt, freq_features, Wf,
                                   bt, bfv, qsize, Wc, bc, Wo, bo,
                                   degT, degF, dsum, cnt, colsb,
                                   Yt, Yf, Zc, feats, Aw, Pt, Pf, Pe, out);
}

// Round 11
// 205.295 us; speedup vs baseline: 1.7345x; 1.7345x over previous
//
#include <hip/hip_runtime.h>
#include <hip/hip_bf16.h>

#define N 2048
#define NM1 2047
#define DT 256
#define ET 32
#define EC 128
#define NC 5
#define FS 80    // feats row stride (floats)
#define FD 69    // used feature cols
#define KC_ET 16 // k-chunks for ET GEMMs (chunk = 128)
#define KC_EC 16 // k-chunks for EC GEMM (chunk = 128)

typedef __hip_bfloat16 bf16;

// ---- fused: deg (blocks 0..511) + label mask (512) + X@W (513..1024) ----
__global__ __launch_bounds__(256) void k_deg_label_xw(const float* __restrict__ tw,
                                                      const float* __restrict__ fw,
                                                      const int* __restrict__ labels,
                                                      const float* __restrict__ Xt,
                                                      const float* __restrict__ Wt,
                                                      const float* __restrict__ Xf,
                                                      const float* __restrict__ Wf,
                                                      float* __restrict__ degT,
                                                      float* __restrict__ degF,
                                                      float* __restrict__ cols,
                                                      float* __restrict__ Yt,
                                                      float* __restrict__ Yf){
    int b = blockIdx.x;
    int t = threadIdx.x;
    if (b < 512){
        // deg via shifted column sums: tw[s][p]=A[d,s], d=p+(p>=s)
        int p = (b & 7)*256 + t;
        if (p >= NM1) return;
        int s0 = (b >> 3)*32;
        float lowT=0.f, highT=0.f, lowF=0.f, highF=0.f;
        #pragma unroll 8
        for (int r = 0; r < 32; ++r){
            int s = s0 + r;
            float vt = tw[(size_t)s*NM1 + p];
            float vf = fw[(size_t)s*NM1 + p];
            if (s <= p){ highT += vt; highF += vf; }
            else       { lowT  += vt; lowF  += vf; }
        }
        atomicAdd(&degT[p],   lowT);
        atomicAdd(&degF[p],   lowF);
        atomicAdd(&degT[p+1], highT);
        atomicAdd(&degF[p+1], highF);
        return;
    }
    if (b == 512){
        __shared__ float lc[NC];
        if (t < NC) lc[t] = 0.f;
        __syncthreads();
        for (int i = t; i < N; i += 256){
            int l = labels[i];
            if (l >= 0 && l < NC) lc[l] = 1.f;
        }
        __syncthreads();
        if (t < NC) cols[t] = lc[t];
        return;
    }
    // X@W (unscaled), 512 blocks: idx 0..511 -> graph, i-block
    int idx = b - 513;
    const float* X = (idx & 256) ? Xf : Xt;
    const float* W = (idx & 256) ? Wf : Wt;
    float*       Y = (idx & 256) ? Yf : Yt;
    __shared__ float Ws[DT*ET];
    __shared__ float Xs[8*DT];
    for (int j = t; j < DT*ET; j += 256) Ws[j] = W[j];
    int i0 = (idx & 255)*8;
    for (int j = t; j < 8*DT; j += 256) Xs[j] = X[(size_t)i0*DT + j];
    __syncthreads();
    int r = t >> 5, f = t & 31;
    const float* xr = Xs + r*DT;
    float acc = 0.f;
    #pragma unroll 8
    for (int d = 0; d < DT; ++d) acc += xr[d]*Ws[d*ET+f];
    Y[(size_t)(i0+r)*ET+f] = acc;
}

// ---- split-K GEMM, both graphs (wave-uniform split); Z scaled at stage ----
__global__ __launch_bounds__(256) void k_agg_et(const float* __restrict__ tw,
                                                const float* __restrict__ fw,
                                                const float* __restrict__ Yt,
                                                const float* __restrict__ Yf,
                                                const float* __restrict__ degT,
                                                const float* __restrict__ degF,
                                                float* __restrict__ Pt,
                                                float* __restrict__ Pf){
    __shared__ float Ast[64*68];   // [k][i]
    __shared__ float Asf[64*68];
    __shared__ float Zst[64*ET];   // [k][f] scaled
    __shared__ float Zsf[64*ET];
    int t = threadIdx.x;
    int i0 = blockIdx.x*64;
    int kc = blockIdx.y;           // 0..15, chunk 128
    int k0 = kc*128;
    int g  = t >> 7;               // wave-uniform graph select
    int tt = t & 127;
    int ig = tt >> 3, fg = tt & 7;
    int r0 = ig*4, c0 = fg*4;
    const float* As = g ? Asf : Ast;
    const float* Zs = g ? Zsf : Zst;
    float acc[4][4];
    #pragma unroll
    for (int u=0;u<4;++u)
        #pragma unroll
        for (int v=0;v<4;++v) acc[u][v]=0.f;

    for (int kt = 0; kt < 2; ++kt){
        int kb = k0 + kt*64;
        #pragma unroll
        for (int e = 0; e < 16; ++e){
            int id = t + e*256;            // 0..4095
            int k_l = id >> 6, i_l = id & 63;
            int k = kb + k_l;
            int gi = i0 + i_l;
            float vt, vf;
            if (gi == k){ vt = 0.f; vf = 0.f; }
            else {
                size_t base = (size_t)k*NM1 + gi - (gi > k ? 1 : 0);
                vt = tw[base]; vf = fw[base];
            }
            Ast[k_l*68 + i_l] = vt;
            Asf[k_l*68 + i_l] = vf;
        }
        #pragma unroll
        for (int e = 0; e < 2; ++e){
            int id = t + e*256;            // 0..511 float4 ids over 64x32
            int row = id >> 3;
            int c4  = (id & 7)*4;
            float rdT = rsqrtf(1.f + degT[kb+row]);
            float rdF = rsqrtf(1.f + degF[kb+row]);
            float4 yt = *(const float4*)&Yt[(size_t)(kb+row)*ET + c4];
            float4 yf = *(const float4*)&Yf[(size_t)(kb+row)*ET + c4];
            yt.x*=rdT; yt.y*=rdT; yt.z*=rdT; yt.w*=rdT;
            yf.x*=rdF; yf.y*=rdF; yf.z*=rdF; yf.w*=rdF;
            *(float4*)&Zst[row*ET + c4] = yt;
            *(float4*)&Zsf[row*ET + c4] = yf;
        }
        __syncthreads();
        for (int k = 0; k < 64; ++k){
            float4 a = *(const float4*)&As[k*68 + r0];
            float4 z = *(const float4*)&Zs[k*ET + c0];
            const float* ap = (const float*)&a;
            const float* zp = (const float*)&z;
            #pragma unroll
            for (int u = 0; u < 4; ++u)
                #pragma unroll
                for (int v = 0; v < 4; ++v)
                    acc[u][v] += ap[u]*zp[v];
        }
        __syncthreads();
    }
    float* P = g ? Pf : Pt;
    #pragma unroll
    for (int u = 0; u < 4; ++u){
        size_t ii = (size_t)(i0 + r0 + u);
        float4 o;
        float* po = (float*)&o;
        #pragma unroll
        for (int v = 0; v < 4; ++v) po[v]=acc[u][v];
        *(float4*)&P[(size_t)kc*(N*ET) + ii*ET + c0] = o;
    }
}

// ---- reduce partials + self term + dis*(.)+bias + lrelu + onehot -> feats ----
__global__ __launch_bounds__(256) void k_feats_epi(const float* __restrict__ Pt,
                                                   const float* __restrict__ Pf,
                                                   const float* __restrict__ Yt,
                                                   const float* __restrict__ Yf,
                                                   const float* __restrict__ degT,
                                                   const float* __restrict__ degF,
                                                   const float* __restrict__ bt,
                                                   const float* __restrict__ bfv,
                                                   const float* __restrict__ cols,
                                                   const int* __restrict__ qsize,
                                                   float* __restrict__ feats){
    int idx = blockIdx.x*256 + threadIdx.x;   // over 2048*64
    int i = idx >> 6;
    int f = idx & 63;
    float s, rd, b;
    if (f < ET){
        rd = rsqrtf(1.f + degT[i]);
        s = rd*Yt[(size_t)i*ET + f];          // self-loop term
        #pragma unroll
        for (int kc = 0; kc < KC_ET; ++kc) s += Pt[(size_t)kc*(N*ET) + (size_t)i*ET + f];
        b = bt[f];
    } else {
        int g = f - ET;
        rd = rsqrtf(1.f + degF[i]);
        s = rd*Yf[(size_t)i*ET + g];
        #pragma unroll
        for (int kc = 0; kc < KC_ET; ++kc) s += Pf[(size_t)kc*(N*ET) + (size_t)i*ET + g];
        b = bfv[g];
    }
    float v = rd*s + b;
    feats[(size_t)i*FS + f] = v > 0.f ? v : 0.01f*v;
    if (f < NC){
        int nsup = N - qsize[0];
        feats[(size_t)i*FS + 2*ET + f] = (i < nsup) ? cols[f] : 0.f;
    }
}

// ---- Aw[i][j] = (i==j) ? 1 : 1/(L1+1e-5); fused row-sum atomics into dsum ----
__global__ __launch_bounds__(256) void k_build_aw(const float* __restrict__ feats,
                                                  float* __restrict__ Aw,
                                                  float* __restrict__ dsum){
    __shared__ float fiT[64*68];   // [dim][row]
    __shared__ float fjT[64*68];
    int t = threadIdx.x;
    int i0 = blockIdx.x*64, j0 = blockIdx.y*64;
    {
        int row = t >> 2;
        int cb  = (t & 3)*16;
        const float4* si = (const float4*)(feats + (size_t)(i0+row)*FS + cb);
        const float4* sj = (const float4*)(feats + (size_t)(j0+row)*FS + cb);
        #pragma unroll
        for (int s = 0; s < 4; ++s){
            float4 v = si[s];
            float4 w = sj[s];
            int c = cb + s*4;
            fiT[(c+0)*68+row]=v.x; fiT[(c+1)*68+row]=v.y; fiT[(c+2)*68+row]=v.z; fiT[(c+3)*68+row]=v.w;
            fjT[(c+0)*68+row]=w.x; fjT[(c+1)*68+row]=w.y; fjT[(c+2)*68+row]=w.z; fjT[(c+3)*68+row]=w.w;
        }
    }
    __syncthreads();
    int tx = t & 15, ty = t >> 4;
    float acc[4][4];
    #pragma unroll
    for (int u=0;u<4;++u)
        #pragma unroll
        for (int v=0;v<4;++v) acc[u][v]=0.f;
    for (int d = 0; d < 64; ++d){
        float4 a4 = *(const float4*)&fiT[d*68 + ty*4];
        float4 b4 = *(const float4*)&fjT[d*68 + tx*4];
        const float* ap = (const float*)&a4;
        const float* bp = (const float*)&b4;
        #pragma unroll
        for (int u = 0; u < 4; ++u)
            #pragma unroll
            for (int v = 0; v < 4; ++v)
                acc[u][v] += fabsf(ap[u]-bp[v]);
    }
    #pragma unroll
    for (int u = 0; u < 4; ++u){
        int gi = i0 + ty*4 + u;
        float4 o;
        float* po = (float*)&o;
        #pragma unroll
        for (int v = 0; v < 4; ++v){
            int gj = j0 + tx*4 + v;
            po[v] = (gi==gj) ? 1.0f : 1.0f/(acc[u][v] + 1e-5f);
        }
        *(float4*)&Aw[(size_t)gi*N + j0 + tx*4] = o;
        float rs = (po[0]+po[1]) + (po[2]+po[3]);
        rs += __shfl_xor(rs, 1);
        rs += __shfl_xor(rs, 2);
        rs += __shfl_xor(rs, 4);
        rs += __shfl_xor(rs, 8);
        if (tx == 0) atomicAdd(&dsum[gi], rs);
    }
}

// ---- Zc[i][f] = rsqrt(dsum[i]) * (feats[i,0:69] @ Wc[:,f]) ----
__global__ __launch_bounds__(256) void k_featswc(const float* __restrict__ feats,
                                                 const float* __restrict__ Wc,
                                                 const float* __restrict__ dsum,
                                                 float* __restrict__ Zc){
    __shared__ float Wcs[FD*EC];
    __shared__ float fr[8][FD+3];
    int t = threadIdx.x; // 256
    for (int idx = t; idx < FD*EC; idx += 256) Wcs[idx] = Wc[idx];
    int i0 = blockIdx.x*8;
    for (int idx = t; idx < 8*FD; idx += 256){
        int r = idx / FD;
        int c = idx - r*FD;
        fr[r][c] = feats[(size_t)(i0+r)*FS + c];
    }
    __syncthreads();
    int f  = t & 127;
    int rh = t >> 7;
    for (int rr = 0; rr < 4; ++rr){
        int r = rh*4 + rr;
        float acc = 0.f;
        #pragma unroll
        for (int d = 0; d < FD; ++d) acc += fr[r][d]*Wcs[d*EC+f];
        int i = i0 + r;
        Zc[(size_t)i*EC + f] = rsqrtf(dsum[i])*acc;
    }
}

// ---- split-K GEMM: Pe[kc][i][f] = sum_{k in chunk} Aw[i,k]*Zc[k][f]
// 64i x 128f tile, grid 32x16=512 blocks (2/CU, 8 waves), 48.4 KB LDS,
// micro 4i x (4+4)f split-column, A staged [k][i] via Aw symmetry.
__global__ __launch_bounds__(256) void k_agg_ec(const float* __restrict__ Aw,
                                                const float* __restrict__ Zc,
                                                float* __restrict__ Pe){
    __shared__ float As[64*68];     // [k][i] 64k x 64i (+pad)
    __shared__ float Zs[64*128];    // [k][f]
    int t = threadIdx.x;
    int i0 = blockIdx.x*64;
    int kc = blockIdx.y;            // 0..15, chunk 128
    int k0 = kc*128;
    int rg = t >> 4;                // 0..15 -> i rows rg*4..+3
    int cg = t & 15;                // cols cg*4 and 64+cg*4
    int r0 = rg*4;
    int ca = cg*4, cb = 64 + cg*4;
    float acc[4][8];
    #pragma unroll
    for (int u=0;u<4;++u)
        #pragma unroll
        for (int v=0;v<8;++v) acc[u][v]=0.f;

    for (int kt = 0; kt < 2; ++kt){
        int kb = k0 + kt*64;
        // stage A via symmetry: As[k][i] = Aw[kb+k][i0+i]  (coalesced rows)
        #pragma unroll
        for (int e = 0; e < 4; ++e){
            int id = t + e*256;          // 0..1023 float4 ids over 64k x 16(i4)
            int k_l = id >> 4;
            int i4  = (id & 15)*4;
            *(float4*)&As[k_l*68 + i4] = *(const float4*)&Aw[(size_t)(kb+k_l)*N + i0 + i4];
        }
        // stage Z
        #pragma unroll
        for (int e = 0; e < 8; ++e){
            int id = t + e*256;          // 0..2047 float4 ids over 64k x 32(f4)
            int k_l = id >> 5;
            int c4  = (id & 31)*4;
            *(float4*)&Zs[k_l*128 + c4] = *(const float4*)&Zc[(size_t)(kb+k_l)*EC + c4];
        }
        __syncthreads();
        for (int k = 0; k < 64; ++k){
            float4 a  = *(const float4*)&As[k*68 + r0];
            float4 z0 = *(const float4*)&Zs[k*128 + ca];
            float4 z1 = *(const float4*)&Zs[k*128 + cb];
            float a4[4] = {a.x,a.y,a.z,a.w};
            float zl[4] = {z0.x,z0.y,z0.z,z0.w};
            float zh[4] = {z1.x,z1.y,z1.z,z1.w};
            #pragma unroll
            for (int u = 0; u < 4; ++u){
                #pragma unroll
                for (int v = 0; v < 4; ++v){
                    acc[u][v]   += a4[u]*zl[v];
                    acc[u][v+4] += a4[u]*zh[v];
                }
            }
        }
        __syncthreads();
    }
    #pragma unroll
    for (int u = 0; u < 4; ++u){
        size_t ii = (size_t)(i0 + r0 + u);
        float4 o0, o1;
        float* p0 = (float*)&o0; float* p1 = (float*)&o1;
        #pragma unroll
        for (int v = 0; v < 4; ++v){ p0[v]=acc[u][v]; p1[v]=acc[u][v+4]; }
        *(float4*)&Pe[(size_t)kc*(N*EC) + ii*EC + ca] = o0;
        *(float4*)&Pe[(size_t)kc*(N*EC) + ii*EC + cb] = o1;
    }
}

// ---- fused: reduce Pe + rsqrt(dsum)*(.)+bc + lrelu -> emb (LDS) -> out ----
__global__ __launch_bounds__(256) void k_embfinal(const float* __restrict__ Pe,
                                                  const float* __restrict__ dsum,
                                                  const float* __restrict__ bc,
                                                  const float* __restrict__ Wo,
                                                  const float* __restrict__ bo,
                                                  float* __restrict__ out){
    __shared__ float vs[2][EC];
    __shared__ float Wos[EC*NC];
    __shared__ float bos[NC];
    int t = threadIdx.x;
    for (int idx = t; idx < EC*NC; idx += 256) Wos[idx] = Wo[idx];
    if (t < NC) bos[t] = bo[t];
    int rr = t >> 7, f = t & 127;
    int i = blockIdx.x*2 + rr;
    size_t idx = (size_t)i*EC + f;
    float s = 0.f;
    #pragma unroll
    for (int kc = 0; kc < KC_EC; ++kc) s += Pe[(size_t)kc*(N*EC) + idx];
    float v = rsqrtf(dsum[i])*s + bc[f];
    vs[rr][f] = v > 0.f ? v : 0.01f*v;
    __syncthreads();
    if (t < 2*NC){
        int r = t / NC;
        int c = t - r*NC;
        float a = bos[c];
        #pragma unroll 8
        for (int f2 = 0; f2 < EC; ++f2) a += vs[r][f2]*Wos[f2*NC+c];
        out[(size_t)(blockIdx.x*2 + r)*NC + c] = a;
    }
}

extern "C" void kernel_launch(void* const* d_in, const int* in_sizes, int n_in,
                              void* d_out, int out_size, void* d_ws, size_t ws_size,
                              hipStream_t stream) {
    const float* time_features = (const float*)d_in[0];
    const float* tw            = (const float*)d_in[2];
    const float* freq_features = (const float*)d_in[3];
    const float* fw            = (const float*)d_in[4];
    const int*   labels        = (const int*)d_in[5];
    const int*   qsize         = (const int*)d_in[7];
    const float* Wt  = (const float*)d_in[8];
    const float* bt  = (const float*)d_in[9];
    const float* Wf  = (const float*)d_in[10];
    const float* bfv = (const float*)d_in[11];
    const float* Wc  = (const float*)d_in[12];
    const float* bc  = (const float*)d_in[13];
    const float* Wo  = (const float*)d_in[14];
    const float* bo  = (const float*)d_in[15];
    float* out = (float*)d_out;

    float* ws    = (float*)d_ws;
    float* Yt    = ws;                         // N*ET (unscaled XW)
    float* Yf    = Yt + (size_t)N*ET;          // N*ET
    float* Zc    = Yf + (size_t)N*ET;          // N*EC
    float* degT  = Zc + (size_t)N*EC;          // N   (zeroed)
    float* degF  = degT + N;                   // N   (zeroed)
    float* dsum  = degF + N;                   // N   (zeroed)
    float* colsb = dsum + N;                   // 8
    float* feats = colsb + 8;                  // N*FS
    float* Aw    = feats + (size_t)N*FS;       // N*N
    float* Pt    = Aw + (size_t)N*N;           // KC_ET*N*ET
    float* Pf    = Pt + (size_t)KC_ET*N*ET;    // KC_ET*N*ET
    float* Pe    = Pf + (size_t)KC_ET*N*ET;    // KC_EC*N*EC

    hipMemsetAsync(degT, 0, 3*N*sizeof(float), stream);
    k_deg_label_xw<<<1025, 256, 0, stream>>>(tw, fw, labels,
                                             time_features, Wt, freq_features, Wf,
                                             degT, degF, colsb, Yt, Yf);
    k_agg_et<<<dim3(N/64, KC_ET), 256, 0, stream>>>(tw, fw, Yt, Yf, degT, degF, Pt, Pf);
    k_feats_epi<<<(N*64)/256, 256, 0, stream>>>(Pt, Pf, Yt, Yf, degT, degF,
                                                bt, bfv, colsb, qsize, feats);
    k_build_aw<<<dim3(N/64, N/64), 256, 0, stream>>>(feats, Aw, dsum);
    k_featswc<<<N/8, 256, 0, stream>>>(feats, Wc, dsum, Zc);
    k_agg_ec<<<dim3(N/64, KC_EC), 256, 0, stream>>>(Aw, Zc, Pe);
    k_embfinal<<<N/2, 256, 0, stream>>>(Pe, dsum, bc, Wo, bo, out);
}